// Round 4
// baseline (5917.411 us; speedup 1.0000x reference)
//
#include <hip/hip_runtime.h>
#include <cstdint>

#define B_ 2
#define N_ 65536
#define C_ 512
#define K_ 64
#define H_ 8
#define EPSV 1e-8f
#define SCALE_ 0.125f

// ---------- Kernel 1: P[b][k][c] = sum_n a[b,n,k]*vox[b,n,c]; dn[b][k] = sum_n a[b,n,k]
__global__ __launch_bounds__(256) void pool_k(const float* __restrict__ vox,
                                              const float* __restrict__ a,
                                              float* __restrict__ P,
                                              float* __restrict__ dn) {
  const int chunk = blockIdx.x;  // 32 chunks of 2048 rows
  const int ct = blockIdx.y;     // 8 c-tiles of 64
  const int b = blockIdx.z;
  __shared__ float a_l[16][64];
  __shared__ float v_l[16][64];
  const int tid = threadIdx.x;
  const int k0 = (tid >> 4) << 2;
  const int c0 = (tid & 15) << 2;
  const int srow = tid >> 4;
  const int sf4 = tid & 15;
  float acc[4][4] = {};
  float asum[4] = {};
  const float* ab = a + ((size_t)b * N_ + (size_t)chunk * 2048) * K_;
  const float* vb = vox + ((size_t)b * N_ + (size_t)chunk * 2048) * C_ + ct * 64;
#pragma unroll 1
  for (int s = 0; s < 128; ++s) {
    __syncthreads();
    *(float4*)&a_l[srow][sf4 * 4] = *(const float4*)&ab[(size_t)(s * 16 + srow) * K_ + sf4 * 4];
    *(float4*)&v_l[srow][sf4 * 4] = *(const float4*)&vb[(size_t)(s * 16 + srow) * C_ + sf4 * 4];
    __syncthreads();
#pragma unroll
    for (int nn = 0; nn < 16; ++nn) {
      float av[4], vv[4];
      *(float4*)av = *(const float4*)&a_l[nn][k0];
      *(float4*)vv = *(const float4*)&v_l[nn][c0];
#pragma unroll
      for (int i = 0; i < 4; ++i) {
        asum[i] += av[i];
#pragma unroll
        for (int j = 0; j < 4; ++j) acc[i][j] += av[i] * vv[j];
      }
    }
  }
  float* Pp = P + ((size_t)b * K_) * C_ + ct * 64;
#pragma unroll
  for (int i = 0; i < 4; ++i)
#pragma unroll
    for (int j = 0; j < 4; ++j) atomicAdd(&Pp[(k0 + i) * C_ + c0 + j], acc[i][j]);
  if (ct == 0 && sf4 == 0) {
#pragma unroll
    for (int i = 0; i < 4; ++i) atomicAdd(&dn[b * K_ + k0 + i], asum[i]);
  }
}

// ---------- Kernel 2a: Pkv[b][k][j] = (P[b,k,:]·wqkv[:,512+j]) / (dn[b,k]+EPS), j in [0,1024)
__global__ __launch_bounds__(256) void pkv_k(const float* __restrict__ wqkv,
                                             const float* __restrict__ P,
                                             const float* __restrict__ dn,
                                             float* __restrict__ Pkv) {
  const int jt = blockIdx.x;  // 16 tiles of 64
  const int b = blockIdx.y;
  __shared__ float P_l[64][20];
  __shared__ float W_l[16][68];
  const int tid = threadIdx.x;
  const int k0 = (tid >> 4) << 2;
  const int j0 = (tid & 15) << 2;
  float acc[4][4] = {};
#pragma unroll 1
  for (int cc0 = 0; cc0 < C_; cc0 += 16) {
    __syncthreads();
    *(float4*)&P_l[tid >> 2][(tid & 3) * 4] =
        *(const float4*)&P[((size_t)b * K_ + (tid >> 2)) * C_ + cc0 + (tid & 3) * 4];
    *(float4*)&W_l[tid >> 4][(tid & 15) * 4] =
        *(const float4*)&wqkv[(size_t)(cc0 + (tid >> 4)) * 1536 + 512 + jt * 64 + (tid & 15) * 4];
    __syncthreads();
#pragma unroll
    for (int cc = 0; cc < 16; ++cc) {
      float pk[4], wv[4];
#pragma unroll
      for (int i = 0; i < 4; ++i) pk[i] = P_l[k0 + i][cc];
      *(float4*)wv = *(const float4*)&W_l[cc][j0];
#pragma unroll
      for (int i = 0; i < 4; ++i)
#pragma unroll
        for (int j = 0; j < 4; ++j) acc[i][j] += pk[i] * wv[j];
    }
  }
#pragma unroll
  for (int i = 0; i < 4; ++i) {
    float dinv = 1.0f / (dn[b * K_ + k0 + i] + EPSV);
#pragma unroll
    for (int j = 0; j < 4; ++j)
      Pkv[((size_t)b * K_ + k0 + i) * 1024 + jt * 64 + j0 + j] = acc[i][j] * dinv;
  }
}

// ---------- Kernel 2b: M[b][c][h*64+k] = SCALE * sum_d wqkv[c][h*64+d]*Pkv[b][k][h*64+d]
__global__ __launch_bounds__(256) void mbuild_k(const float* __restrict__ wqkv,
                                                const float* __restrict__ Pkv,
                                                float* __restrict__ M) {
  const int ct = blockIdx.x;  // 4 tiles of 128 c
  const int h = blockIdx.y;
  const int b = blockIdx.z;
  __shared__ float Pk_l[64][68];
  __shared__ float Wq_l[128][68];
  const int tid = threadIdx.x;
#pragma unroll
  for (int t = 0; t < 4; ++t) {
    int idx = t * 256 + tid;
    *(float4*)&Pk_l[idx >> 4][(idx & 15) * 4] =
        *(const float4*)&Pkv[((size_t)b * K_ + (idx >> 4)) * 1024 + h * 64 + (idx & 15) * 4];
  }
#pragma unroll
  for (int t = 0; t < 8; ++t) {
    int idx = t * 256 + tid;
    *(float4*)&Wq_l[idx >> 4][(idx & 15) * 4] =
        *(const float4*)&wqkv[(size_t)(ct * 128 + (idx >> 4)) * 1536 + h * 64 + (idx & 15) * 4];
  }
  __syncthreads();
  const int cg = (tid >> 3) << 2;
  const int kg = (tid & 7) << 3;
  float acc[4][8] = {};
#pragma unroll 4
  for (int d = 0; d < 64; ++d) {
    float wq[4], pk[8];
#pragma unroll
    for (int i = 0; i < 4; ++i) wq[i] = Wq_l[cg + i][d];
#pragma unroll
    for (int j = 0; j < 8; ++j) pk[j] = Pk_l[kg + j][d];
#pragma unroll
    for (int i = 0; i < 4; ++i)
#pragma unroll
      for (int j = 0; j < 8; ++j) acc[i][j] += wq[i] * pk[j];
  }
  float* Mb = M + (size_t)b * 576 * 512;
#pragma unroll
  for (int i = 0; i < 4; ++i)
#pragma unroll
    for (int j = 0; j < 8; ++j)
      Mb[(size_t)(ct * 128 + cg + i) * 512 + h * 64 + kg + j] = SCALE_ * acc[i][j];
}

// ---------- Kernel 2b2: bias rows of M: M[b][512+j][h*64+k] = cb[j][k]
__global__ void mbias_k(const float* __restrict__ cb, float* __restrict__ M) {
  const int j = blockIdx.x;
  const int b = blockIdx.y;
  const int t = threadIdx.x;  // 512
  M[(size_t)b * 576 * 512 + (size_t)(512 + j) * 512 + t] = cb[j * 64 + (t & 63)];
}

// ---------- Kernel 2c: VW[b][h*64+k][c] = sum_d Pkv[b][k][512+h*64+d]*wproj[h*64+d][c]
__global__ __launch_bounds__(256) void vw_k(const float* __restrict__ wproj,
                                            const float* __restrict__ Pkv,
                                            float* __restrict__ VW) {
  const int ct = blockIdx.x;  // 4 tiles of 128 c
  const int h = blockIdx.y;
  const int b = blockIdx.z;
  __shared__ float Pv_l[64][68];
  __shared__ float Wp_l[64][132];
  const int tid = threadIdx.x;
#pragma unroll
  for (int t = 0; t < 4; ++t) {
    int idx = t * 256 + tid;
    *(float4*)&Pv_l[idx >> 4][(idx & 15) * 4] =
        *(const float4*)&Pkv[((size_t)b * K_ + (idx >> 4)) * 1024 + 512 + h * 64 + (idx & 15) * 4];
  }
#pragma unroll
  for (int t = 0; t < 8; ++t) {
    int idx = t * 256 + tid;
    *(float4*)&Wp_l[idx >> 5][(idx & 31) * 4] =
        *(const float4*)&wproj[(size_t)(h * 64 + (idx >> 5)) * 512 + ct * 128 + (idx & 31) * 4];
  }
  __syncthreads();
  const int kg = (tid >> 5) << 3;
  const int cg = (tid & 31) << 2;
  float acc[8][4] = {};
#pragma unroll 4
  for (int d = 0; d < 64; ++d) {
    float pv[8], wp[4];
#pragma unroll
    for (int j = 0; j < 8; ++j) pv[j] = Pv_l[kg + j][d];
    *(float4*)wp = *(const float4*)&Wp_l[d][cg];
#pragma unroll
    for (int j = 0; j < 8; ++j)
#pragma unroll
      for (int i = 0; i < 4; ++i) acc[j][i] += pv[j] * wp[i];
  }
  float* VWb = VW + (size_t)b * 512 * 512;
#pragma unroll
  for (int j = 0; j < 8; ++j)
    *(float4*)&VWb[(size_t)(h * 64 + kg + j) * 512 + ct * 128 + cg] = *(float4*)acc[j];
}

// ---------- fused_k phase 3 body: HALF is compile-time so acc3 stays in registers
template <int HALF>
__device__ __forceinline__ void phase3_body(const float* __restrict__ VWb,
                                            const float* __restrict__ At,
                                            float* __restrict__ Wx, int tid, int r0,
                                            int cl, float acc3[8][4]) {
  float4 wpre[4];
#pragma unroll
  for (int t = 0; t < 4; ++t) {
    int idx = t * 256 + tid;
    wpre[t] = *(const float4*)&VWb[(size_t)(idx >> 6) * 512 + HALF * 256 + (idx & 63) * 4];
  }
#pragma unroll 1
  for (int kc0 = 0; kc0 < 512; kc0 += 16) {
    __syncthreads();  // prior iteration's Wx reads complete
#pragma unroll
    for (int t = 0; t < 4; ++t) {
      int idx = t * 256 + tid;
      *(float4*)&Wx[(idx >> 6) * 256 + (idx & 63) * 4] = wpre[t];
    }
    if (kc0 + 16 < 512) {  // prefetch next chunk; latency hides under compute
#pragma unroll
      for (int t = 0; t < 4; ++t) {
        int idx = t * 256 + tid;
        wpre[t] = *(const float4*)&VWb[(size_t)(kc0 + 16 + (idx >> 6)) * 512 + HALF * 256 +
                                       (idx & 63) * 4];
      }
    }
    __syncthreads();
#pragma unroll
    for (int kq = 0; kq < 4; ++kq) {
      float4 ar[8];
#pragma unroll
      for (int i = 0; i < 8; ++i) ar[i] = *(const float4*)&At[(r0 + i) * 512 + kc0 + kq * 4];
#pragma unroll
      for (int kk = 0; kk < 4; ++kk) {
        float bvv[4];
        *(float4*)bvv = *(const float4*)&Wx[(kq * 4 + kk) * 256 + cl];
#pragma unroll
        for (int i = 0; i < 8; ++i) {
          float av = (&ar[i].x)[kk];
#pragma unroll
          for (int j = 0; j < 4; ++j) acc3[i][j] += av * bvv[j];
        }
      }
    }
  }
}

// ---------- Kernel 3: fused [vox|a]@M -> group softmax -> @VW + b_proj
__global__ __launch_bounds__(256) void fused_k(const float* __restrict__ vox,
                                               const float* __restrict__ a,
                                               const float* __restrict__ M,
                                               const float* __restrict__ VW,
                                               const float* __restrict__ bproj,
                                               float* __restrict__ out) {
  // XCD-aware remap: lin%8 = XCD (measured m09); give each XCD one batch so its
  // 4MB L2 holds that batch's M+VW (2.2MB) instead of both (4.4MB).
  const int lin = blockIdx.x;
  const int b = (lin >> 2) & 1;
  const int tile = (lin >> 3) * 4 + (lin & 3);
  const int n0 = tile * 32;
  __shared__ __align__(16) char smem[81920];
  float* At = (float*)smem;            // [32][512] 64KB (phases 2-3)
  float* Mx = (float*)smem;            // [16][512] 32KB (phase 1, overlays At)
  float* Vx = (float*)(smem + 32768);  // [16][33]  (phase 1, transposed, padded)
  float* Wx = (float*)(smem + 65536);  // [16][256] 16KB (phase 3)
  const int tid = threadIdx.x;
  const int lane = tid & 63;
  const int wave = tid >> 6;
  const int r0 = wave * 8;
  const int cl = lane * 4;
  const float* Mb = M + (size_t)b * 576 * 512;
  const float* voxb = vox + (size_t)b * N_ * C_;
  const float* ab2 = a + (size_t)b * N_ * K_;
  // Vx element ids: e in [0,512): vr=e>>4 (row 0..31), vc=e&15 (col 0..15)
  const int vr0 = tid >> 4, vc0 = tid & 15;          // e = tid
  const int vr1 = (tid + 256) >> 4, vc1 = tid & 15;  // e = tid+256

  // ---- phase 1: S = [vox|a] @ M, register-prefetched staging (T14), KC=16
  float acc[8][8] = {};
  float4 mpre[8];
  float vpre0, vpre1;
#pragma unroll
  for (int t = 0; t < 8; ++t) {
    int idx = t * 256 + tid;
    mpre[t] = *(const float4*)&Mb[(size_t)(idx >> 7) * 512 + (idx & 127) * 4];
  }
  vpre0 = voxb[(size_t)(n0 + vr0) * C_ + vc0];
  vpre1 = voxb[(size_t)(n0 + vr1) * C_ + vc1];
#pragma unroll 1
  for (int kc0 = 0; kc0 < 576; kc0 += 16) {
    __syncthreads();  // prior compute's LDS reads done
#pragma unroll
    for (int t = 0; t < 8; ++t) {
      int idx = t * 256 + tid;
      *(float4*)&Mx[(idx >> 7) * 512 + (idx & 127) * 4] = mpre[t];
    }
    Vx[vc0 * 33 + vr0] = vpre0;
    Vx[vc1 * 33 + vr1] = vpre1;
    if (kc0 + 16 < 576) {  // prefetch next chunk
      const int kn = kc0 + 16;
#pragma unroll
      for (int t = 0; t < 8; ++t) {
        int idx = t * 256 + tid;
        mpre[t] = *(const float4*)&Mb[(size_t)(kn + (idx >> 7)) * 512 + (idx & 127) * 4];
      }
      if (kn < 512) {
        vpre0 = voxb[(size_t)(n0 + vr0) * C_ + kn + vc0];
        vpre1 = voxb[(size_t)(n0 + vr1) * C_ + kn + vc1];
      } else {
        vpre0 = ab2[(size_t)(n0 + vr0) * K_ + (kn - 512) + vc0];
        vpre1 = ab2[(size_t)(n0 + vr1) * K_ + (kn - 512) + vc1];
      }
    }
    __syncthreads();
#pragma unroll
    for (int kk = 0; kk < 16; ++kk) {
      float av[8], bv[8];
      *(float4*)&av[0] = *(const float4*)&Vx[kk * 33 + r0];
      *(float4*)&av[4] = *(const float4*)&Vx[kk * 33 + r0 + 4];
      *(float4*)&bv[0] = *(const float4*)&Mx[kk * 512 + cl];
      *(float4*)&bv[4] = *(const float4*)&Mx[kk * 512 + 256 + cl];
#pragma unroll
      for (int i = 0; i < 8; ++i)
#pragma unroll
        for (int j = 0; j < 8; ++j) acc[i][j] += av[i] * bv[j];
    }
  }
  __syncthreads();  // all phase-1 LDS reads done before At overwrites Mx/Vx region

  // ---- phase 2: softmax over 64-col head groups (16-lane subgroups)
#pragma unroll
  for (int i = 0; i < 8; ++i) {
    float mlo = fmaxf(fmaxf(acc[i][0], acc[i][1]), fmaxf(acc[i][2], acc[i][3]));
    float mhi = fmaxf(fmaxf(acc[i][4], acc[i][5]), fmaxf(acc[i][6], acc[i][7]));
#pragma unroll
    for (int m = 1; m <= 8; m <<= 1) {
      mlo = fmaxf(mlo, __shfl_xor(mlo, m, 64));
      mhi = fmaxf(mhi, __shfl_xor(mhi, m, 64));
    }
    float slo = 0.f, shi = 0.f;
#pragma unroll
    for (int j = 0; j < 4; ++j) { acc[i][j] = __expf(acc[i][j] - mlo); slo += acc[i][j]; }
#pragma unroll
    for (int j = 4; j < 8; ++j) { acc[i][j] = __expf(acc[i][j] - mhi); shi += acc[i][j]; }
#pragma unroll
    for (int m = 1; m <= 8; m <<= 1) {
      slo += __shfl_xor(slo, m, 64);
      shi += __shfl_xor(shi, m, 64);
    }
    float rlo = 1.0f / slo, rhi = 1.0f / shi;
#pragma unroll
    for (int j = 0; j < 4; ++j) acc[i][j] *= rlo;
#pragma unroll
    for (int j = 4; j < 8; ++j) acc[i][j] *= rhi;
    *(float4*)&At[(r0 + i) * 512 + cl] = *(float4*)&acc[i][0];
    *(float4*)&At[(r0 + i) * 512 + 256 + cl] = *(float4*)&acc[i][4];
  }

  // ---- phase 3: out = At @ VW + b_proj (two static halves; acc stays in VGPRs)
  const float* VWb = VW + (size_t)b * 512 * 512;
  float acc3a[8][4] = {};
  float acc3b[8][4] = {};
  phase3_body<0>(VWb, At, Wx, tid, r0, cl, acc3a);
  phase3_body<1>(VWb, At, Wx, tid, r0, cl, acc3b);

  float bp0[4], bp1[4];
  *(float4*)bp0 = *(const float4*)&bproj[cl];
  *(float4*)bp1 = *(const float4*)&bproj[256 + cl];
  float* ob = out + (size_t)b * N_ * C_;
#pragma unroll
  for (int i = 0; i < 8; ++i) {
    float4 lo = make_float4(acc3a[i][0] + bp0[0], acc3a[i][1] + bp0[1],
                            acc3a[i][2] + bp0[2], acc3a[i][3] + bp0[3]);
    float4 hi = make_float4(acc3b[i][0] + bp1[0], acc3b[i][1] + bp1[1],
                            acc3b[i][2] + bp1[2], acc3b[i][3] + bp1[3]);
    *(float4*)&ob[(size_t)(n0 + r0 + i) * C_ + cl] = lo;
    *(float4*)&ob[(size_t)(n0 + r0 + i) * C_ + 256 + cl] = hi;
  }
}

extern "C" void kernel_launch(void* const* d_in, const int* in_sizes, int n_in,
                              void* d_out, int out_size, void* d_ws, size_t ws_size,
                              hipStream_t stream) {
  const float* vox = (const float*)d_in[0];
  const float* a = (const float*)d_in[1];
  const float* wqkv = (const float*)d_in[2];
  const float* wproj = (const float*)d_in[3];
  const float* bproj = (const float*)d_in[4];
  const float* cb = (const float*)d_in[5];
  float* out = (float*)d_out;
  float* ws = (float*)d_ws;
  float* P = ws;               // 65536 floats
  float* dn = ws + 65536;      // 128
  float* Pkv = ws + 65664;     // 131072
  float* M = ws + 196736;      // 589824  (2 x 576 x 512)
  float* VW = ws + 786560;     // 524288  (2 x 512 x 512)

  hipMemsetAsync(P, 0, (65536 + 128) * sizeof(float), stream);
  hipLaunchKernelGGL(pool_k, dim3(32, 8, 2), dim3(256), 0, stream, vox, a, P, dn);
  hipLaunchKernelGGL(pkv_k, dim3(16, 2), dim3(256), 0, stream, wqkv, P, dn, Pkv);
  hipLaunchKernelGGL(mbuild_k, dim3(4, 8, 2), dim3(256), 0, stream, wqkv, Pkv, M);
  hipLaunchKernelGGL(mbias_k, dim3(64, 2), dim3(512), 0, stream, cb, M);
  hipLaunchKernelGGL(vw_k, dim3(4, 8, 2), dim3(256), 0, stream, wproj, Pkv, VW);
  hipLaunchKernelGGL(fused_k, dim3(4096), dim3(256), 0, stream, vox, a, M, VW, bproj, out);
}

// Round 5
// 3063.932 us; speedup vs baseline: 1.9313x; 1.9313x over previous
//
#include <hip/hip_runtime.h>
#include <cstdint>

#define B_ 2
#define N_ 65536
#define C_ 512
#define K_ 64
#define H_ 8
#define EPSV 1e-8f
#define SCALE_ 0.125f

// ---------- Kernel 1: P[b][k][c] = sum_n a[b,n,k]*vox[b,n,c]; dn[b][k] = sum_n a[b,n,k]
__global__ __launch_bounds__(256) void pool_k(const float* __restrict__ vox,
                                              const float* __restrict__ a,
                                              float* __restrict__ P,
                                              float* __restrict__ dn) {
  const int chunk = blockIdx.x;  // 32 chunks of 2048 rows
  const int ct = blockIdx.y;     // 8 c-tiles of 64
  const int b = blockIdx.z;
  __shared__ float a_l[16][64];
  __shared__ float v_l[16][64];
  const int tid = threadIdx.x;
  const int k0 = (tid >> 4) << 2;
  const int c0 = (tid & 15) << 2;
  const int srow = tid >> 4;
  const int sf4 = tid & 15;
  float acc[4][4] = {};
  float asum[4] = {};
  const float* ab = a + ((size_t)b * N_ + (size_t)chunk * 2048) * K_;
  const float* vb = vox + ((size_t)b * N_ + (size_t)chunk * 2048) * C_ + ct * 64;
#pragma unroll 1
  for (int s = 0; s < 128; ++s) {
    __syncthreads();
    *(float4*)&a_l[srow][sf4 * 4] = *(const float4*)&ab[(size_t)(s * 16 + srow) * K_ + sf4 * 4];
    *(float4*)&v_l[srow][sf4 * 4] = *(const float4*)&vb[(size_t)(s * 16 + srow) * C_ + sf4 * 4];
    __syncthreads();
#pragma unroll
    for (int nn = 0; nn < 16; ++nn) {
      float av[4], vv[4];
      *(float4*)av = *(const float4*)&a_l[nn][k0];
      *(float4*)vv = *(const float4*)&v_l[nn][c0];
#pragma unroll
      for (int i = 0; i < 4; ++i) {
        asum[i] += av[i];
#pragma unroll
        for (int j = 0; j < 4; ++j) acc[i][j] += av[i] * vv[j];
      }
    }
  }
  float* Pp = P + ((size_t)b * K_) * C_ + ct * 64;
#pragma unroll
  for (int i = 0; i < 4; ++i)
#pragma unroll
    for (int j = 0; j < 4; ++j) atomicAdd(&Pp[(k0 + i) * C_ + c0 + j], acc[i][j]);
  if (ct == 0 && sf4 == 0) {
#pragma unroll
    for (int i = 0; i < 4; ++i) atomicAdd(&dn[b * K_ + k0 + i], asum[i]);
  }
}

// ---------- Kernel 2a: Pkv[b][k][j] = (P[b,k,:]·wqkv[:,512+j]) / (dn[b,k]+EPS), j in [0,1024)
__global__ __launch_bounds__(256) void pkv_k(const float* __restrict__ wqkv,
                                             const float* __restrict__ P,
                                             const float* __restrict__ dn,
                                             float* __restrict__ Pkv) {
  const int jt = blockIdx.x;  // 16 tiles of 64
  const int b = blockIdx.y;
  __shared__ float P_l[64][20];
  __shared__ float W_l[16][68];
  const int tid = threadIdx.x;
  const int k0 = (tid >> 4) << 2;
  const int j0 = (tid & 15) << 2;
  float acc[4][4] = {};
#pragma unroll 1
  for (int cc0 = 0; cc0 < C_; cc0 += 16) {
    __syncthreads();
    *(float4*)&P_l[tid >> 2][(tid & 3) * 4] =
        *(const float4*)&P[((size_t)b * K_ + (tid >> 2)) * C_ + cc0 + (tid & 3) * 4];
    *(float4*)&W_l[tid >> 4][(tid & 15) * 4] =
        *(const float4*)&wqkv[(size_t)(cc0 + (tid >> 4)) * 1536 + 512 + jt * 64 + (tid & 15) * 4];
    __syncthreads();
#pragma unroll
    for (int cc = 0; cc < 16; ++cc) {
      float pk[4], wv[4];
#pragma unroll
      for (int i = 0; i < 4; ++i) pk[i] = P_l[k0 + i][cc];
      *(float4*)wv = *(const float4*)&W_l[cc][j0];
#pragma unroll
      for (int i = 0; i < 4; ++i)
#pragma unroll
        for (int j = 0; j < 4; ++j) acc[i][j] += pk[i] * wv[j];
    }
  }
#pragma unroll
  for (int i = 0; i < 4; ++i) {
    float dinv = 1.0f / (dn[b * K_ + k0 + i] + EPSV);
#pragma unroll
    for (int j = 0; j < 4; ++j)
      Pkv[((size_t)b * K_ + k0 + i) * 1024 + jt * 64 + j0 + j] = acc[i][j] * dinv;
  }
}

// ---------- Kernel 2b: M[b][c][h*64+k] = SCALE * sum_d wqkv[c][h*64+d]*Pkv[b][k][h*64+d]
__global__ __launch_bounds__(256) void mbuild_k(const float* __restrict__ wqkv,
                                                const float* __restrict__ Pkv,
                                                float* __restrict__ M) {
  const int ct = blockIdx.x;  // 4 tiles of 128 c
  const int h = blockIdx.y;
  const int b = blockIdx.z;
  __shared__ float Pk_l[64][68];
  __shared__ float Wq_l[128][68];
  const int tid = threadIdx.x;
#pragma unroll
  for (int t = 0; t < 4; ++t) {
    int idx = t * 256 + tid;
    *(float4*)&Pk_l[idx >> 4][(idx & 15) * 4] =
        *(const float4*)&Pkv[((size_t)b * K_ + (idx >> 4)) * 1024 + h * 64 + (idx & 15) * 4];
  }
#pragma unroll
  for (int t = 0; t < 8; ++t) {
    int idx = t * 256 + tid;
    *(float4*)&Wq_l[idx >> 4][(idx & 15) * 4] =
        *(const float4*)&wqkv[(size_t)(ct * 128 + (idx >> 4)) * 1536 + h * 64 + (idx & 15) * 4];
  }
  __syncthreads();
  const int cg = (tid >> 3) << 2;
  const int kg = (tid & 7) << 3;
  float acc[4][8] = {};
#pragma unroll 4
  for (int d = 0; d < 64; ++d) {
    float wq[4], pk[8];
#pragma unroll
    for (int i = 0; i < 4; ++i) wq[i] = Wq_l[cg + i][d];
#pragma unroll
    for (int j = 0; j < 8; ++j) pk[j] = Pk_l[kg + j][d];
#pragma unroll
    for (int i = 0; i < 4; ++i)
#pragma unroll
      for (int j = 0; j < 8; ++j) acc[i][j] += wq[i] * pk[j];
  }
  float* Mb = M + (size_t)b * 576 * 512;
#pragma unroll
  for (int i = 0; i < 4; ++i)
#pragma unroll
    for (int j = 0; j < 8; ++j)
      Mb[(size_t)(ct * 128 + cg + i) * 512 + h * 64 + kg + j] = SCALE_ * acc[i][j];
}

// ---------- Kernel 2b2: bias rows of M: M[b][512+j][h*64+k] = cb[j][k]
__global__ void mbias_k(const float* __restrict__ cb, float* __restrict__ M) {
  const int j = blockIdx.x;
  const int b = blockIdx.y;
  const int t = threadIdx.x;  // 512
  M[(size_t)b * 576 * 512 + (size_t)(512 + j) * 512 + t] = cb[j * 64 + (t & 63)];
}

// ---------- Kernel 2c: VW[b][h*64+k][c] = sum_d Pkv[b][k][512+h*64+d]*wproj[h*64+d][c]
__global__ __launch_bounds__(256) void vw_k(const float* __restrict__ wproj,
                                            const float* __restrict__ Pkv,
                                            float* __restrict__ VW) {
  const int ct = blockIdx.x;  // 4 tiles of 128 c
  const int h = blockIdx.y;
  const int b = blockIdx.z;
  __shared__ float Pv_l[64][68];
  __shared__ float Wp_l[64][132];
  const int tid = threadIdx.x;
#pragma unroll
  for (int t = 0; t < 4; ++t) {
    int idx = t * 256 + tid;
    *(float4*)&Pv_l[idx >> 4][(idx & 15) * 4] =
        *(const float4*)&Pkv[((size_t)b * K_ + (idx >> 4)) * 1024 + 512 + h * 64 + (idx & 15) * 4];
  }
#pragma unroll
  for (int t = 0; t < 8; ++t) {
    int idx = t * 256 + tid;
    *(float4*)&Wp_l[idx >> 5][(idx & 31) * 4] =
        *(const float4*)&wproj[(size_t)(h * 64 + (idx >> 5)) * 512 + ct * 128 + (idx & 31) * 4];
  }
  __syncthreads();
  const int kg = (tid >> 5) << 3;
  const int cg = (tid & 31) << 2;
  float acc[8][4] = {};
#pragma unroll 4
  for (int d = 0; d < 64; ++d) {
    float pv[8], wp[4];
#pragma unroll
    for (int j = 0; j < 8; ++j) pv[j] = Pv_l[kg + j][d];
    *(float4*)wp = *(const float4*)&Wp_l[d][cg];
#pragma unroll
    for (int j = 0; j < 8; ++j)
#pragma unroll
      for (int i = 0; i < 4; ++i) acc[j][i] += pv[j] * wp[i];
  }
  float* VWb = VW + (size_t)b * 512 * 512;
#pragma unroll
  for (int j = 0; j < 8; ++j)
    *(float4*)&VWb[(size_t)(h * 64 + kg + j) * 512 + ct * 128 + cg] = *(float4*)acc[j];
}

// ---------- Kernel 3a: S = [vox|a] @ M -> group softmax -> At (stored in d_out)
// Tile: 64 rows x 256 cols (one col-half). LDS ~20 KB -> occupancy VGPR-bound ~4 waves/SIMD.
__global__ __launch_bounds__(256) void sm_k(const float* __restrict__ vox,
                                            const float* __restrict__ a,
                                            const float* __restrict__ M,
                                            float* __restrict__ At) {
  const int rowtile = blockIdx.x;  // 0..2047
  const int half = blockIdx.y;     // 0..1
  const int b = rowtile >> 10;
  const int n0 = (rowtile & 1023) << 6;  // *64
  __shared__ __align__(16) float Mx[16 * 256];  // 16 KB: M chunk [16 k][256 cols]
  __shared__ __align__(16) float Vx[16 * 68];   // 4.3 KB: [16 k][64 rows + pad4]
  const int tid = threadIdx.x;
  const int lane = tid & 63;
  const int wave = tid >> 6;
  const int r0 = wave << 4;  // 16 rows per wave
  const int cl = lane << 2;  // 4 cols per lane, [0,256)
  const float* Mb = M + (size_t)b * 576 * 512 + half * 256;
  const float* voxb = vox + ((size_t)b * N_ + n0) * C_;
  const float* ab = a + ((size_t)b * N_ + n0) * K_;
  const int vr = tid & 63;  // stage: row within tile
  const int vq = tid >> 6;  // stage: k-quad (0..3)

  float acc[16][4] = {};
  float4 mpre[4];
  float4 vpre;
#pragma unroll
  for (int t = 0; t < 4; ++t) {
    int f4 = t * 256 + tid;
    mpre[t] = *(const float4*)&Mb[(size_t)(f4 >> 6) * 512 + (f4 & 63) * 4];
  }
  vpre = *(const float4*)&voxb[(size_t)vr * C_ + vq * 4];
#pragma unroll 1
  for (int kc0 = 0; kc0 < 576; kc0 += 16) {
    __syncthreads();  // prior compute's LDS reads done
#pragma unroll
    for (int t = 0; t < 4; ++t) {
      int f4 = t * 256 + tid;
      *(float4*)&Mx[(f4 >> 6) * 256 + (f4 & 63) * 4] = mpre[t];
    }
#pragma unroll
    for (int q = 0; q < 4; ++q) Vx[(vq * 4 + q) * 68 + vr] = (&vpre.x)[q];
    if (kc0 + 16 < 576) {  // prefetch next chunk (T14)
      const int kn = kc0 + 16;
#pragma unroll
      for (int t = 0; t < 4; ++t) {
        int f4 = t * 256 + tid;
        mpre[t] = *(const float4*)&Mb[(size_t)(kn + (f4 >> 6)) * 512 + (f4 & 63) * 4];
      }
      vpre = (kn < 512) ? *(const float4*)&voxb[(size_t)vr * C_ + kn + vq * 4]
                        : *(const float4*)&ab[(size_t)vr * K_ + (kn - 512) + vq * 4];
    }
    __syncthreads();
#pragma unroll
    for (int kk = 0; kk < 16; ++kk) {
      __align__(16) float av[16];
      float bv[4];
      *(float4*)&av[0] = *(const float4*)&Vx[kk * 68 + r0];       // wave-uniform broadcast
      *(float4*)&av[4] = *(const float4*)&Vx[kk * 68 + r0 + 4];
      *(float4*)&av[8] = *(const float4*)&Vx[kk * 68 + r0 + 8];
      *(float4*)&av[12] = *(const float4*)&Vx[kk * 68 + r0 + 12];
      *(float4*)bv = *(const float4*)&Mx[kk * 256 + cl];
#pragma unroll
      for (int i = 0; i < 16; ++i)
#pragma unroll
        for (int j = 0; j < 4; ++j) acc[i][j] += av[i] * bv[j];
    }
  }

  // softmax over 64-col head groups (16-lane subgroups), then write At
#pragma unroll
  for (int i = 0; i < 16; ++i) {
    float m = fmaxf(fmaxf(acc[i][0], acc[i][1]), fmaxf(acc[i][2], acc[i][3]));
#pragma unroll
    for (int msk = 1; msk <= 8; msk <<= 1) m = fmaxf(m, __shfl_xor(m, msk, 64));
    float s = 0.f;
#pragma unroll
    for (int j = 0; j < 4; ++j) { acc[i][j] = __expf(acc[i][j] - m); s += acc[i][j]; }
#pragma unroll
    for (int msk = 1; msk <= 8; msk <<= 1) s += __shfl_xor(s, msk, 64);
    float r = 1.0f / s;
#pragma unroll
    for (int j = 0; j < 4; ++j) acc[i][j] *= r;
    *(float4*)&At[((size_t)b * N_ + n0 + r0 + i) * 512 + half * 256 + cl] = *(float4*)&acc[i][0];
  }
}

// ---------- Kernel 3b: out = At @ VW + b_proj (At read from d_out, out overwrites same rows)
// Tile: 32 rows x 512 cols. Block is self-contained on its 32 rows -> no cross-block hazard.
__global__ __launch_bounds__(256) void out_k(const float* __restrict__ At,
                                             const float* __restrict__ VW,
                                             const float* __restrict__ bproj,
                                             float* __restrict__ out) {
  const int rowtile = blockIdx.x;  // 0..4095
  const int b = rowtile >> 11;
  const int n0 = (rowtile & 2047) << 5;  // *32
  const size_t gn0 = (size_t)b * N_ + n0;
  __shared__ __align__(16) float Wx[8 * 512];  // 16 KB: VW chunk [8 k][512 cols]
  __shared__ __align__(16) float Ax[32 * 36];  // 4.6 KB: At chunk [32 rows][32 k + pad4]
  const int tid = threadIdx.x;
  const int lane = tid & 63;
  const int wave = tid >> 6;
  const int r0 = wave << 3;  // 8 rows per wave
  const int cl = lane << 2;  // 4 cols per lane (plus +256 twin)
  const float* VWb = VW + (size_t)b * 512 * 512;
  const int vr = tid & 31;  // At stage: row
  const int vq = tid >> 5;  // At stage: k-quad (0..7)

  float acc[8][8] = {};
  float4 wpre[4];
  float4 apre;
  apre = *(const float4*)&At[(gn0 + vr) * 512 + vq * 4];
#pragma unroll
  for (int t = 0; t < 4; ++t) {
    int f4 = t * 256 + tid;
    wpre[t] = *(const float4*)&VWb[(size_t)(f4 >> 7) * 512 + (f4 & 127) * 4];
  }
#pragma unroll 1
  for (int kc0 = 0; kc0 < 512; kc0 += 32) {
    __syncthreads();  // prior Ax/Wx reads done
    *(float4*)&Ax[vr * 36 + vq * 4] = apre;
    if (kc0 + 32 < 512) apre = *(const float4*)&At[(gn0 + vr) * 512 + kc0 + 32 + vq * 4];
#pragma unroll 1
    for (int sub = 0; sub < 4; ++sub) {
      if (sub) __syncthreads();  // prior Wx reads done
#pragma unroll
      for (int t = 0; t < 4; ++t) {
        int f4 = t * 256 + tid;
        *(float4*)&Wx[(f4 >> 7) * 512 + (f4 & 127) * 4] = wpre[t];
      }
      const int kcn = kc0 + (sub + 1) * 8;
      if (kcn < 512) {
#pragma unroll
        for (int t = 0; t < 4; ++t) {
          int f4 = t * 256 + tid;
          wpre[t] = *(const float4*)&VWb[(size_t)(kcn + (f4 >> 7)) * 512 + (f4 & 127) * 4];
        }
      }
      __syncthreads();
#pragma unroll
      for (int kk = 0; kk < 8; ++kk) {
        float av[8], bvl[4], bvh[4];
#pragma unroll
        for (int i = 0; i < 8; ++i) av[i] = Ax[(r0 + i) * 36 + sub * 8 + kk];  // broadcast
        *(float4*)bvl = *(const float4*)&Wx[kk * 512 + cl];
        *(float4*)bvh = *(const float4*)&Wx[kk * 512 + 256 + cl];
#pragma unroll
        for (int i = 0; i < 8; ++i) {
#pragma unroll
          for (int j = 0; j < 4; ++j) {
            acc[i][j] += av[i] * bvl[j];
            acc[i][4 + j] += av[i] * bvh[j];
          }
        }
      }
    }
  }

  float bp0[4], bp1[4];
  *(float4*)bp0 = *(const float4*)&bproj[cl];
  *(float4*)bp1 = *(const float4*)&bproj[256 + cl];
#pragma unroll
  for (int i = 0; i < 8; ++i) {
    float4 lo = make_float4(acc[i][0] + bp0[0], acc[i][1] + bp0[1], acc[i][2] + bp0[2],
                            acc[i][3] + bp0[3]);
    float4 hi = make_float4(acc[i][4] + bp1[0], acc[i][5] + bp1[1], acc[i][6] + bp1[2],
                            acc[i][7] + bp1[3]);
    *(float4*)&out[(gn0 + r0 + i) * 512 + cl] = lo;
    *(float4*)&out[(gn0 + r0 + i) * 512 + 256 + cl] = hi;
  }
}

extern "C" void kernel_launch(void* const* d_in, const int* in_sizes, int n_in,
                              void* d_out, int out_size, void* d_ws, size_t ws_size,
                              hipStream_t stream) {
  const float* vox = (const float*)d_in[0];
  const float* a = (const float*)d_in[1];
  const float* wqkv = (const float*)d_in[2];
  const float* wproj = (const float*)d_in[3];
  const float* bproj = (const float*)d_in[4];
  const float* cb = (const float*)d_in[5];
  float* out = (float*)d_out;
  float* ws = (float*)d_ws;
  float* P = ws;               // 65536 floats
  float* dn = ws + 65536;      // 128
  float* Pkv = ws + 65664;     // 131072
  float* M = ws + 196736;      // 589824  (2 x 576 x 512)
  float* VW = ws + 786560;     // 524288  (2 x 512 x 512)

  hipMemsetAsync(P, 0, (65536 + 128) * sizeof(float), stream);
  hipLaunchKernelGGL(pool_k, dim3(32, 8, 2), dim3(256), 0, stream, vox, a, P, dn);
  hipLaunchKernelGGL(pkv_k, dim3(16, 2), dim3(256), 0, stream, wqkv, P, dn, Pkv);
  hipLaunchKernelGGL(mbuild_k, dim3(4, 8, 2), dim3(256), 0, stream, wqkv, Pkv, M);
  hipLaunchKernelGGL(mbias_k, dim3(64, 2), dim3(512), 0, stream, cb, M);
  hipLaunchKernelGGL(vw_k, dim3(4, 8, 2), dim3(256), 0, stream, wproj, Pkv, VW);
  // At lives in d_out; sm_k fills every element, out_k overwrites its own rows only.
  hipLaunchKernelGGL(sm_k, dim3(2048, 2), dim3(256), 0, stream, vox, a, M, out);
  hipLaunchKernelGGL(out_k, dim3(4096), dim3(256), 0, stream, out, VW, bproj, out);
}